// Round 11
// baseline (97.657 us; speedup 1.0000x reference)
//
#include <hip/hip_runtime.h>

#define BB 4
#define CC 32
#define HH 512
#define WW 512
#define TS 16
#define SWP 36          // LDS row pitch in floats (9 chunks of 4); bank rotates 4/row
#define WIN 1024        // floats per buffer: rows 0..27 full + partial r=28 (pad)
#define ROWS_OK 26      // taps need r0+1 <= 27
#define COLS_OK 34      // taps need c0+1 <= 35

typedef float f2v __attribute__((ext_vector_type(2), aligned(4)));
typedef const __attribute__((address_space(1))) float gfloat;
typedef __attribute__((address_space(3))) float lfloat;

template<int N> __device__ __forceinline__ void waitvm() {
    asm volatile("s_waitcnt vmcnt(%0)" :: "n"(N) : "memory");
}

__device__ __forceinline__ void stage16(const float* g, float* l) {
    // async global->LDS: per-lane contiguous 16B src, linear LDS dest
    // (wave-uniform base + lane*16B)
    __builtin_amdgcn_global_load_lds((gfloat*)g, (lfloat*)l, 16, 0, 0);
}

__global__ __launch_bounds__(256) void warp_bilinear_kernel(
    const float* __restrict__ src,
    const float* __restrict__ flow,
    float* __restrict__ out)
{
    const int HW = HH * WW;
    // 4 waves x 2 buffers x 4KB = 32 KB; wave-private slabs -> ZERO barriers
    __shared__ float smem[4 * 2 * WIN];

    // Bijective XCD swizzle (gridDim.x == 4096, divisible by 8).
    int nper = gridDim.x >> 3;
    int bid = (blockIdx.x & 7) * nper + (blockIdx.x >> 3);

    int b  = bid >> 10;
    int ty = (bid >> 5) & 31;
    int tx = bid & 31;

    int tid  = threadIdx.x;
    int lane = tid & 63;
    int wv   = tid >> 6;        // wave wv owns channels [wv*8, wv*8+8)

    int lx = lane & 15;
    int ly = lane >> 4;         // 0..3; lane handles pixels (4j+ly, lx), j=0..3

    int tile_row = ty * TS, tile_col = tx * TS;
    int row_base = tile_row - 4, col_base = tile_col - 4;

    const float* sb = src + (size_t)b * CC * HW;
    float*       ob = out + (size_t)b * CC * HW;

    // Channel-invariant staging sources: chunk q = it*64+lane -> LDS float
    // q*4 == r*36 + c4 exactly (9 chunks/row). Per-chunk clamps: interior
    // tiles unaffected; edge tiles put clamped data only in never-read slots
    // (x0>=0 -> c0>=4 when col_base<0; x0<=510 -> c0<=18 when col_base=492).
    int soff[4];
    #pragma unroll
    for (int it = 0; it < 4; ++it) {
        int q  = it * 64 + lane;          // 0..255
        int r  = q / 9;                   // 0..28
        int c4 = (q - r * 9) << 2;        // 0,4,...,32
        int srow = min(max(row_base + r, 0), HH - 1);
        int scol = min(max(col_base + c4, 0), WW - 4);
        soff[it] = srow * WW + scol;
    }

    // Per-sub-iter sampling state (4 pixels per lane).
    float w00[4], w01[4], w10[4], w11[4];
    int lbase[4], i0g[4], pst[4];
    bool intile[4];
    #pragma unroll
    for (int j = 0; j < 4; ++j) {
        int h = tile_row + j * 4 + ly;
        int w = tile_col + lx;
        int p = h * WW + w;
        pst[j] = p;
        float fy = __builtin_nontemporal_load(flow + (b * 2 + 0) * HW + p);
        float fx = __builtin_nontemporal_load(flow + (b * 2 + 1) * HW + p);
        float yy = fminf(fmaxf((float)h + fy, 0.0f), (float)(HH - 1));
        float xx = fminf(fmaxf((float)w + fx, 0.0f), (float)(WW - 1));
        // Border fold (== reference exactly): far tap gets weight exactly 0/1.
        int y0 = min((int)floorf(yy), HH - 2);
        int x0 = min((int)floorf(xx), WW - 2);
        float wy = yy - (float)y0;
        float wx = xx - (float)x0;
        w00[j] = (1.0f - wy) * (1.0f - wx);
        w01[j] = (1.0f - wy) * wx;
        w10[j] = wy * (1.0f - wx);
        w11[j] = wy * wx;
        int r0 = y0 - row_base, c0 = x0 - col_base;
        intile[j] = ((unsigned)r0 <= ROWS_OK) && ((unsigned)c0 <= COLS_OK);
        int rc  = min(max(r0, 0), ROWS_OK);
        int cc2 = min(max(c0, 0), COLS_OK);
        lbase[j] = rc * SWP + cc2;        // taps: +0,+1,+SWP,+SWP+1
        i0g[j] = y0 * WW + x0;            // rare out-of-halo fallback
    }

    float* lwb = smem + wv * (2 * WIN);
    const int ch0 = wv * 8;

    auto stage = [&](int k) {             // k = 0..7 (wave-local channel)
        const float* s = sb + (size_t)(ch0 + k) * HW;
        float* buf = lwb + (k & 1) * WIN;
        #pragma unroll
        for (int it = 0; it < 4; ++it)
            stage16(s + soff[it], buf + it * 256);
    };

    auto compute = [&](int k) {
        const float* lb = lwb + (k & 1) * WIN;
        const float* s  = sb + (size_t)(ch0 + k) * HW;
        float*       o  = ob + (size_t)(ch0 + k) * HW;
        #pragma unroll
        for (int j = 0; j < 4; ++j) {
            float v = lb[lbase[j]]       * w00[j] + lb[lbase[j] + 1]       * w01[j]
                    + lb[lbase[j] + SWP] * w10[j] + lb[lbase[j] + SWP + 1] * w11[j];
            if (!intile[j]) {             // execz-skipped ~99.8% of waves
                f2v t  = *(const f2v*)(s + i0g[j]);
                f2v bt = *(const f2v*)(s + i0g[j] + WW);
                v = t.x * w00[j] + t.y * w01[j] + bt.x * w10[j] + bt.y * w11[j];
            }
            __builtin_nontemporal_store(v, o + pst[j]);
        }
    };

    // Barrier-free per-wave pipeline. VMEM queue at waitvm<8> (oldest first):
    // stage(k)x4, stores(k-1)x4, stage(k+1)x4 -> allowing 8 newest in flight
    // guarantees stage(k) retired (in-order VMEM retirement). Fallback loads
    // only add NEWER entries -> waits stay conservative. Never vmcnt(0).
    stage(0);
    stage(1);
    waitvm<4>();
    compute(0);
    #pragma unroll
    for (int k = 1; k <= 6; ++k) {
        stage(k + 1);
        waitvm<8>();
        compute(k);
    }
    waitvm<4>();
    compute(7);
}

extern "C" void kernel_launch(void* const* d_in, const int* in_sizes, int n_in,
                              void* d_out, int out_size, void* d_ws, size_t ws_size,
                              hipStream_t stream) {
    const float* src  = (const float*)d_in[0];
    const float* flow = (const float*)d_in[1];
    float* out = (float*)d_out;

    const int nblocks = BB * (HH / TS) * (WW / TS);   // 4096, divisible by 8
    warp_bilinear_kernel<<<nblocks, 256, 0, stream>>>(src, flow, out);
}